// Round 6
// baseline (196.042 us; speedup 1.0000x reference)
//
#include <hip/hip_runtime.h>
#include <hip/hip_bf16.h>

typedef float f32x4 __attribute__((ext_vector_type(4)));
typedef short s16x8 __attribute__((ext_vector_type(8)));

#define NROWS 8192
#define KDIM  1024
#define BM 128
#define BN 128
#define BK 64
#define NKT (KDIM / BK)                // 16 K-steps
#define NTILE (NROWS / BM)             // 64 tile-rows
#define NBLK (NTILE * (NTILE + 1) / 2) // 2080 upper-tri blocks

// round-to-nearest-even fp32 -> bf16 bits, also returns the rounded-back fp32 value
__device__ __forceinline__ unsigned short f2bf(float f, float& back) {
    union { float f; unsigned u; } a; a.f = f;
    unsigned r = a.u + 0x7fffu + ((a.u >> 16) & 1u);
    unsigned short b = (unsigned short)(r >> 16);
    union { unsigned u; float f; } c; c.u = ((unsigned)b) << 16;
    back = c.f;
    return b;
}

__device__ __forceinline__ void gl_lds16(const unsigned short* g, unsigned short* l) {
    __builtin_amdgcn_global_load_lds(
        (const __attribute__((address_space(1))) void*)g,
        (__attribute__((address_space(3))) void*)l, 16, 0, 0);
}

__global__ __launch_bounds__(256)
void prep_kernel(const float* __restrict__ in, unsigned short* __restrict__ abf,
                 float* __restrict__ sq) {
    const int row = blockIdx.x;
    const int t = threadIdx.x;
    const float4 v = reinterpret_cast<const float4*>(in + (size_t)row * KDIM)[t];
    float b0, b1, b2, b3;
    ushort4 u;
    u.x = f2bf(v.x, b0);
    u.y = f2bf(v.y, b1);
    u.z = f2bf(v.z, b2);
    u.w = f2bf(v.w, b3);
    reinterpret_cast<ushort4*>(abf + (size_t)row * KDIM)[t] = u;
    float s = b0 * b0 + b1 * b1 + b2 * b2 + b3 * b3;
    #pragma unroll
    for (int off = 32; off > 0; off >>= 1) s += __shfl_down(s, off);
    __shared__ float red[4];
    if ((t & 63) == 0) red[t >> 6] = s;
    __syncthreads();
    if (t == 0) sq[row] = red[0] + red[1] + red[2] + red[3];
}

// C = A*A^T upper-tri tiles, 128x128, BK=64, 4 waves (2x2 of 64x64), 2-phase
// loop (R1's proven sync), 16 K-steps (half the barriers of BK=32).
// LDS is FRAGMENT-MAJOR (R4's proven conflict-free layout): lds[mat][f][kk]
// is one 16x32 MFMA fragment as a 1KB lane-ordered block -- gl_lds writes it
// linearly (uniform base + lane*16B) and ds_read_b128 reads it lane-contiguous
// (0 bank conflicts, measured R4). Fragment element permutation is baked into
// per-lane GLOBAL source addresses (m173). Accumulation order bitwise matches
// R1 -> absmax must stay 0.25.
// Fused epilogue -sqrt(max(sqi+sqj-2c,0)); off-diag tiles mirror-written
// (reg index r contiguous in transposed address -> one float4 per fragment).
__global__ __launch_bounds__(256)
void gemm_kernel(const unsigned short* __restrict__ A, const float* __restrict__ sq,
                 float* __restrict__ out) {
    // [mat 0=A,1=B][fragment row/col 0..7][k-half 0..1][512 elems] = 32 KB
    __shared__ __attribute__((aligned(16))) unsigned short lds[2][8][2][512];

    // XCD-aware swizzle: 2080 blocks, 2080 % 8 == 0 -> bijective
    const int bid = blockIdx.x;
    const int cpx = NBLK >> 3;  // 260
    const int swz = (bid & 7) * cpx + (bid >> 3);

    // triangular decode: swz -> (bi, bj), bi <= bj; tiles in rows < r: r*(129-r)/2
    int bi = (int)((129.0f - sqrtf(129.0f * 129.0f - 8.0f * (float)swz)) * 0.5f);
    if (bi > NTILE - 1) bi = NTILE - 1;
    if (bi < 0) bi = 0;
    while ((bi + 1) * (129 - (bi + 1)) / 2 <= swz) ++bi;
    while (bi * (129 - bi) / 2 > swz) --bi;
    const int bj = bi + (swz - bi * (129 - bi) / 2);

    const int brow = bi * BM;
    const int bcol = bj * BN;

    const int t = threadIdx.x;
    const int lane = t & 63;
    const int w = t >> 6;      // 0..3
    const int wr = w >> 1;     // 0..1
    const int wc = w & 1;      // 0..1
    const int l15 = lane & 15, l4 = lane >> 4;

    // ---- staging: wave w owns 8 of the 32 1KB fragment blocks ----
    // block b (0..7): fragment f = (w&1)*4 + (b>>1), k-half kk = b&1
    // matrix: w<2 -> A panel (rows brow+...), w>=2 -> B panel (rows bcol+...)
    const int mat = w >> 1;
    const int fb = (w & 1) * 4;
    const int tbase = mat ? bcol : brow;
    const unsigned short* gp[8];
    unsigned short* lp[8];
    #pragma unroll
    for (int b = 0; b < 8; ++b) {
        const int f = fb + (b >> 1), kk = b & 1;
        // element (row f*16 + l15, k kk*32 + l4*8 + 0..7) -> lds pos lane*8
        gp[b] = A + (size_t)(tbase + f * 16 + l15) * KDIM + kk * 32 + l4 * 8;
        lp[b] = &lds[mat][f][kk][0];
    }

    f32x4 acc[4][4] = {};

    for (int kt = 0; kt < NKT; ++kt) {
        #pragma unroll
        for (int b = 0; b < 8; ++b)
            gl_lds16(gp[b] + kt * BK, lp[b]);
        __syncthreads();

        s16x8 af[4][2], bf[4][2];
        #pragma unroll
        for (int m = 0; m < 4; ++m)
            #pragma unroll
            for (int kk = 0; kk < 2; ++kk)
                af[m][kk] = *reinterpret_cast<const s16x8*>(&lds[0][wr * 4 + m][kk][lane * 8]);
        #pragma unroll
        for (int n = 0; n < 4; ++n)
            #pragma unroll
            for (int kk = 0; kk < 2; ++kk)
                bf[n][kk] = *reinterpret_cast<const s16x8*>(&lds[1][wc * 4 + n][kk][lane * 8]);

        #pragma unroll
        for (int m = 0; m < 4; ++m)
            #pragma unroll
            for (int n = 0; n < 4; ++n) {
                acc[m][n] = __builtin_amdgcn_mfma_f32_16x16x32_bf16(af[m][0], bf[n][0], acc[m][n], 0, 0, 0);
                acc[m][n] = __builtin_amdgcn_mfma_f32_16x16x32_bf16(af[m][1], bf[n][1], acc[m][n], 0, 0, 0);
            }
        __syncthreads();
    }

    // epilogue: C/D layout col = lane&15, row = (lane>>4)*4 + reg [m89/m91]
    const int ib = brow + wr * 64 + l4 * 4;
    const int jb = bcol + wc * 64 + l15;
    float sqj[4];
    #pragma unroll
    for (int n = 0; n < 4; ++n) sqj[n] = sq[jb + n * 16];

    const bool offdiag = (bi != bj);
    #pragma unroll
    for (int m = 0; m < 4; ++m) {
        #pragma unroll
        for (int n = 0; n < 4; ++n) {
            f32x4 tv;
            #pragma unroll
            for (int r = 0; r < 4; ++r) {
                const int i = ib + m * 16 + r;
                const float d2 = sq[i] + sqj[n] - 2.0f * acc[m][n][r];
                tv[r] = -sqrtf(fmaxf(d2, 0.0f));
            }
            #pragma unroll
            for (int r = 0; r < 4; ++r) {
                const int i = ib + m * 16 + r;
                out[(size_t)i * NROWS + (jb + n * 16)] = tv[r];
            }
            if (offdiag) {
                const size_t mrow = (size_t)(jb + n * 16) * NROWS + (ib + m * 16);
                *reinterpret_cast<float4*>(&out[mrow]) = *(float4*)&tv;
            }
        }
    }
}

extern "C" void kernel_launch(void* const* d_in, const int* in_sizes, int n_in,
                              void* d_out, int out_size, void* d_ws, size_t ws_size,
                              hipStream_t stream) {
    const float* feat = (const float*)d_in[0];
    float* out = (float*)d_out;
    unsigned short* abf = (unsigned short*)d_ws;                       // 16 MB bf16 copy
    float* sq = (float*)((char*)d_ws + (size_t)NROWS * KDIM * 2);      // 32 KB row sums

    prep_kernel<<<NROWS, 256, 0, stream>>>(feat, abf, sq);
    gemm_kernel<<<NBLK, 256, 0, stream>>>(abf, sq, out);
}